// Round 6
// baseline (926.725 us; speedup 1.0000x reference)
//
#include <hip/hip_runtime.h>
#include <stdint.h>

#define NE 500000
#define NN 50000
#define ND 256
#define ED 128
#define GD 64
#define MAXDEG 64

typedef float f4v __attribute__((ext_vector_type(4)));
typedef short s8v __attribute__((ext_vector_type(8)));
typedef short s4v __attribute__((ext_vector_type(4)));

static __device__ __forceinline__ short f2bf(float f) {
  union { float f; uint32_t u; } v; v.f = f;
  uint32_t r = v.u + 0x7FFFu + ((v.u >> 16) & 1u);
  return (short)(r >> 16);
}
static __device__ __forceinline__ float bf2f(uint32_t u) {
  union { uint32_t u; float f; } v; v.u = u << 16; return v.f;
}

// ---- convert fp32 -> bf16 (vectorized x4) ----
__global__ void cvt_bf16_kernel(const float* __restrict__ src, short* __restrict__ dst, int n) {
  int i = (blockIdx.x * blockDim.x + threadIdx.x) * 4;
  if (i >= n) return;
  const float4 v = *(const float4*)(src + i);
  s4v o; o[0] = f2bf(v.x); o[1] = f2bf(v.y); o[2] = f2bf(v.z); o[3] = f2bf(v.w);
  *(s4v*)(dst + i) = o;
}

// ---- pack W[K][C] row-major fp32 -> bf16 MFMA fragment order [ks][c][kh][j] ----
__global__ void pack_w_kernel(const float* __restrict__ src, short* __restrict__ dst, int K, int C) {
  int idx = blockIdx.x * blockDim.x + threadIdx.x;
  if (idx >= K * C) return;
  int k = idx / C, c = idx - k * C;
  int ks = k >> 5, kh = (k >> 3) & 3, j = k & 7;
  dst[(((ks * C + c) * 4 + kh) << 3) + j] = f2bf(src[idx]);
}

// ---- counting sort of edges by source row ----
__global__ void hist_kernel(const int* __restrict__ erow, unsigned int* __restrict__ rcnt) {
  int e = blockIdx.x * blockDim.x + threadIdx.x;
  if (e >= NE) return;
  atomicAdd(&rcnt[erow[e]], 1u);
}

__global__ void scan_kernel(const unsigned int* __restrict__ rcnt, int* __restrict__ rbase) {
  __shared__ int part[1024];
  const int t = threadIdx.x;
  const int CH = (NN + 1023) / 1024;           // 49
  int lo = t * CH, hi = lo + CH; if (hi > NN) hi = NN; if (lo > NN) lo = NN;
  int s = 0;
  for (int i = lo; i < hi; ++i) s += (int)rcnt[i];
  part[t] = s;
  __syncthreads();
  for (int d = 1; d < 1024; d <<= 1) {
    int o = (t >= d) ? part[t - d] : 0;
    __syncthreads();
    part[t] += o;
    __syncthreads();
  }
  int running = part[t] - s;                   // exclusive prefix of this chunk
  for (int i = lo; i < hi; ++i) { rbase[i] = running; running += (int)rcnt[i]; }
}

// ---- scatter into sorted order AND build per-destination lists over slots ----
__global__ void scatter_build_kernel(const int* __restrict__ erow,
                                     const int* __restrict__ ecol,
                                     const int* __restrict__ rbase,
                                     unsigned int* __restrict__ rcur,
                                     int* __restrict__ order, int* __restrict__ srow,
                                     unsigned int* __restrict__ cnt,
                                     int* __restrict__ elist) {
  int e = blockIdx.x * blockDim.x + threadIdx.x;
  if (e >= NE) return;
  int r = erow[e];
  int s = rbase[r] + (int)atomicAdd(&rcur[r], 1u);
  order[s] = e;
  srow[s] = r;
  int c = ecol[e];
  unsigned int slot = atomicAdd(&cnt[c], 1u);
  if (slot < MAXDEG) elist[c * MAXDEG + slot] = s;
}

// ---- build per-destination lists over raw edge ids (fallback path) ----
__global__ void build_kernel(const int* __restrict__ ecol, unsigned int* __restrict__ cnt,
                             int* __restrict__ elist) {
  int e = blockIdx.x * blockDim.x + threadIdx.x;
  if (e >= NE) return;
  int c = ecol[e];
  unsigned int slot = atomicAdd(&cnt[c], 1u);
  if (slot < MAXDEG) elist[c * MAXDEG + slot] = e;
}

// ---- gather-mean: one wave per node, lane handles 2 dims ----
__global__ void agg_kernel(const unsigned short* __restrict__ ebuf,
                           const int* __restrict__ elist,
                           const unsigned int* __restrict__ cnt,
                           unsigned short* __restrict__ aggbf) {
  int tid = threadIdx.x;
  int lane = tid & 63;
  int node = blockIdx.x * 4 + (tid >> 6);
  if (node >= NN) return;
  unsigned int deg = cnt[node];
  unsigned int jend = deg < MAXDEG ? deg : MAXDEG;
  float a0 = 0.f, a1 = 0.f;
  const int* el = elist + (size_t)node * MAXDEG;
  for (unsigned int j = 0; j < jend; ++j) {
    int eid = el[j];
    uint32_t v = *(const uint32_t*)(ebuf + (size_t)eid * ED + 2 * lane);
    a0 += bf2f(v & 0xFFFFu);
    a1 += bf2f(v >> 16);
  }
  float rc = 1.0f / (deg > 0 ? (float)deg : 1.0f);
  uint32_t o = (uint32_t)(uint16_t)f2bf(a0 * rc) | ((uint32_t)(uint16_t)f2bf(a1 * rc) << 16);
  *(uint32_t*)(aggbf + (size_t)node * ED + 2 * lane) = o;
}

// =======================================================================
// hx kernel: hx[50K][512] = xbf @ W1[0:256,:]  (dense, per-node, bf16 out)
// =======================================================================
__launch_bounds__(512, 4)
__global__ void hx_kernel(const short* __restrict__ xbf,
                          const short* __restrict__ w1xp,
                          short* __restrict__ hx) {
  __shared__ __align__(16) short smem[64 * 256];
  const int tid = threadIdx.x;
  const int lane = tid & 63;
  const int w = tid >> 6;
  const int lh = lane >> 4;
  const int ll = lane & 15;
  const int n0 = blockIdx.x * 64;

  #pragma unroll
  for (int it = 0; it < 4; ++it) {
    int ch = tid + it * 512;
    int rr = ch >> 5, cc = (ch & 31) * 8;
    s8v vals = {0, 0, 0, 0, 0, 0, 0, 0};
    if (n0 + rr < NN) vals = *(const s8v*)(xbf + (size_t)(n0 + rr) * ND + cc);
    int byte = (rr * 512 + cc * 2) ^ ((rr & 7) << 4);
    *(s8v*)((char*)smem + byte) = vals;
  }
  __syncthreads();

  f4v acc[4][4];
  #pragma unroll
  for (int n = 0; n < 4; ++n)
    #pragma unroll
    for (int m = 0; m < 4; ++m)
      acc[n][m] = (f4v){0.f, 0.f, 0.f, 0.f};

  for (int ks = 0; ks < 8; ++ks) {
    s8v hf[4];
    #pragma unroll
    for (int m = 0; m < 4; ++m) {
      int row = 16 * m + ll;
      int byte = (row * 512 + ks * 64 + lh * 16) ^ ((row & 7) << 4);
      hf[m] = *(const s8v*)((const char*)smem + byte);
    }
    #pragma unroll
    for (int n = 0; n < 4; ++n) {
      s8v wf = *(const s8v*)(w1xp + (((ks * 512 + w * 64 + 16 * n + ll) * 4 + lh) << 3));
      #pragma unroll
      for (int m = 0; m < 4; ++m)
        acc[n][m] = __builtin_amdgcn_mfma_f32_16x16x32_bf16(wf, hf[m], acc[n][m], 0, 0, 0);
    }
  }

  #pragma unroll
  for (int n = 0; n < 4; ++n) {
    int cb = w * 64 + 16 * n + 4 * lh;
    #pragma unroll
    for (int m = 0; m < 4; ++m) {
      int node = n0 + 16 * m + ll;
      if (node < NN) {
        s4v o;
        o[0] = f2bf(acc[n][m][0]);
        o[1] = f2bf(acc[n][m][1]);
        o[2] = f2bf(acc[n][m][2]);
        o[3] = f2bf(acc[n][m][3]);
        *(s4v*)(hx + (size_t)node * 512 + cb) = o;
      }
    }
  }
}

// =======================================================================
// Edge kernel. MODE 2 (sorted+hx): slots s = blockIdx*64.., rows from srow
// (sorted -> ~7 distinct rows/block), ea via order[] (1-touch 512B rows),
// GEMM1 K=128 + hx add; GEMM2 K=512; output staged in LDS then stored as
// full-line coalesced 16B/thread writes (no partial-line L2 merging).
// MODE 0 (fallback): unsorted, GEMM1 K=384 on [x[row]||ea].
// =======================================================================
template <int MODE>
__launch_bounds__(512, 4)
__global__ void edge_kernel(const short* __restrict__ xbf,
                            const short* __restrict__ hx,
                            const float* __restrict__ edge_attr,
                            const short* __restrict__ w1p,
                            const float* __restrict__ b1,
                            const short* __restrict__ w2p,
                            const float* __restrict__ b2,
                            const int* __restrict__ erow,
                            const int* __restrict__ order,
                            const int* __restrict__ srow,
                            unsigned short* __restrict__ ebuf) {
  __shared__ __align__(16) short smem[64 * 512];
  __shared__ int rid[64], eo[64];
  const int tid = threadIdx.x;
  const int lane = tid & 63;
  const int w = tid >> 6;
  const int lh = lane >> 4;
  const int ll = lane & 15;
  const int e0 = blockIdx.x * 64;

  if (tid < 64) {
    int s = e0 + tid;
    if constexpr (MODE == 2) {
      if (s < NE) { rid[tid] = srow[s]; eo[tid] = order[s]; }
      else { rid[tid] = 0; eo[tid] = 0; }
    } else {
      rid[tid] = (s < NE) ? erow[s] : 0;
    }
  }
  __syncthreads();

  // ---- stage A1 bf16 first (gates GEMM1), XOR-swizzled rows ----
  s4v hxg[4][4];
  if constexpr (MODE == 2) {
    #pragma unroll
    for (int it = 0; it < 2; ++it) {
      int ch = tid + it * 512;
      int rr = ch >> 4, cc = (ch & 15) * 8;
      s8v vals = {0, 0, 0, 0, 0, 0, 0, 0};
      if (e0 + rr < NE) {
        const float* p = edge_attr + (size_t)eo[rr] * ED + cc;
        const float4 v0 = *(const float4*)(p);
        const float4 v1 = *(const float4*)(p + 4);
        vals[0] = f2bf(v0.x); vals[1] = f2bf(v0.y); vals[2] = f2bf(v0.z); vals[3] = f2bf(v0.w);
        vals[4] = f2bf(v1.x); vals[5] = f2bf(v1.y); vals[6] = f2bf(v1.z); vals[7] = f2bf(v1.w);
      }
      int byte = (rr * 256 + cc * 2) ^ ((rr & 7) << 4);
      *(s8v*)((char*)smem + byte) = vals;
    }
    // ---- issue hx gather now; results consumed after GEMM1 ----
    int ridm[4];
    #pragma unroll
    for (int m = 0; m < 4; ++m) ridm[m] = rid[16 * m + ll];
    #pragma unroll
    for (int n = 0; n < 4; ++n) {
      int cb = w * 64 + 16 * n + 4 * lh;
      #pragma unroll
      for (int m = 0; m < 4; ++m)
        hxg[n][m] = *(const s4v*)(hx + (size_t)ridm[m] * 512 + cb);
    }
  } else {
    #pragma unroll
    for (int it = 0; it < 6; ++it) {
      int ch = tid + it * 512;
      int rr = ch / 48;
      int cc = (ch - rr * 48) * 8;
      s8v vals = {0, 0, 0, 0, 0, 0, 0, 0};
      if (e0 + rr < NE) {
        if (cc < ND) {
          vals = *(const s8v*)(xbf + (size_t)rid[rr] * ND + cc);
        } else {
          const float* p = edge_attr + (size_t)(e0 + rr) * ED + (cc - ND);
          const float4 v0 = *(const float4*)(p);
          const float4 v1 = *(const float4*)(p + 4);
          vals[0] = f2bf(v0.x); vals[1] = f2bf(v0.y); vals[2] = f2bf(v0.z); vals[3] = f2bf(v0.w);
          vals[4] = f2bf(v1.x); vals[5] = f2bf(v1.y); vals[6] = f2bf(v1.z); vals[7] = f2bf(v1.w);
        }
      }
      int byte = (rr * 768 + cc * 2) ^ ((rr & 7) << 4);
      *(s8v*)((char*)smem + byte) = vals;
    }
  }
  __syncthreads();

  // ---- GEMM1 (swapped) ----
  constexpr int KS1 = (MODE == 2) ? 4 : 12;
  constexpr int AST = (MODE == 2) ? 256 : 768;
  f4v acc1[4][4];
  #pragma unroll
  for (int n = 0; n < 4; ++n)
    #pragma unroll
    for (int m = 0; m < 4; ++m)
      acc1[n][m] = (f4v){0.f, 0.f, 0.f, 0.f};

  for (int ks = 0; ks < KS1; ++ks) {
    s8v hf[4];
    #pragma unroll
    for (int m = 0; m < 4; ++m) {
      int row = 16 * m + ll;
      int byte = (row * AST + ks * 64 + lh * 16) ^ ((row & 7) << 4);
      hf[m] = *(const s8v*)((const char*)smem + byte);
    }
    #pragma unroll
    for (int n = 0; n < 4; ++n) {
      s8v wf = *(const s8v*)(w1p + (((ks * 512 + w * 64 + 16 * n + ll) * 4 + lh) << 3));
      #pragma unroll
      for (int m = 0; m < 4; ++m)
        acc1[n][m] = __builtin_amdgcn_mfma_f32_16x16x32_bf16(wf, hf[m], acc1[n][m], 0, 0, 0);
    }
  }
  __syncthreads();

  // ---- H1 = relu(acc1 [+ hx] + b1) -> LDS [64][512] bf16 swizzled ----
  #pragma unroll
  for (int n = 0; n < 4; ++n) {
    int cb = w * 64 + 16 * n + 4 * lh;
    const float4 bv = *(const float4*)(b1 + cb);
    #pragma unroll
    for (int m = 0; m < 4; ++m) {
      int row = 16 * m + ll;
      float v0 = acc1[n][m][0] + bv.x;
      float v1 = acc1[n][m][1] + bv.y;
      float v2 = acc1[n][m][2] + bv.z;
      float v3 = acc1[n][m][3] + bv.w;
      if constexpr (MODE == 2) {
        v0 += bf2f((uint32_t)(uint16_t)hxg[n][m][0]);
        v1 += bf2f((uint32_t)(uint16_t)hxg[n][m][1]);
        v2 += bf2f((uint32_t)(uint16_t)hxg[n][m][2]);
        v3 += bf2f((uint32_t)(uint16_t)hxg[n][m][3]);
      }
      s4v o;
      o[0] = f2bf(v0 > 0.f ? v0 : 0.f);
      o[1] = f2bf(v1 > 0.f ? v1 : 0.f);
      o[2] = f2bf(v2 > 0.f ? v2 : 0.f);
      o[3] = f2bf(v3 > 0.f ? v3 : 0.f);
      int byte = (row * 1024 + cb * 2) ^ ((row & 7) << 4);
      *(s4v*)((char*)smem + byte) = o;
    }
  }
  __syncthreads();

  // ---- GEMM2 (swapped), K=512 ----
  f4v acc2[4];
  #pragma unroll
  for (int m = 0; m < 4; ++m)
    acc2[m] = (f4v){0.f, 0.f, 0.f, 0.f};

  for (int ks = 0; ks < 16; ++ks) {
    s8v wf = *(const s8v*)(w2p + (((ks * 128 + w * 16 + ll) * 4 + lh) << 3));
    #pragma unroll
    for (int m = 0; m < 4; ++m) {
      int row = 16 * m + ll;
      int byte = (row * 1024 + ks * 64 + lh * 16) ^ ((row & 7) << 4);
      s8v hf = *(const s8v*)((const char*)smem + byte);
      acc2[m] = __builtin_amdgcn_mfma_f32_16x16x32_bf16(wf, hf, acc2[m], 0, 0, 0);
    }
  }
  __syncthreads();   // all H1 reads done; reuse smem[0..16KB) for output tile

  // ---- stage output tile [64][128] bf16 in LDS (swizzled) ----
  {
    int cb = w * 16 + 4 * lh;
    const float4 bv = *(const float4*)(b2 + cb);
    #pragma unroll
    for (int m = 0; m < 4; ++m) {
      int row = 16 * m + ll;
      s4v o;
      o[0] = f2bf(acc2[m][0] + bv.x);
      o[1] = f2bf(acc2[m][1] + bv.y);
      o[2] = f2bf(acc2[m][2] + bv.z);
      o[3] = f2bf(acc2[m][3] + bv.w);
      int byte = (row * 256 + cb * 2) ^ ((row & 7) << 4);
      *(s4v*)((char*)smem + byte) = o;
    }
  }
  __syncthreads();

  // ---- coalesced store: each wave writes 1KB contiguous ----
  {
    size_t g0 = (size_t)e0 * ED;        // elements
    #pragma unroll
    for (int it = 0; it < 2; ++it) {
      int B = (tid + it * 512) * 16;    // byte offset in [0,16384)
      int row = B >> 8;
      int lb = B ^ ((row & 7) << 4);
      s8v v = *(const s8v*)((const char*)smem + lb);
      if (e0 + row < NE)
        *(s8v*)((char*)(ebuf + g0) + B) = v;
    }
  }
}

// =======================================================================
// Node kernel: unchanged.
// =======================================================================
__launch_bounds__(512, 2)
__global__ void node_kernel(const float* __restrict__ x,
                            const short* __restrict__ xbf,
                            const float* __restrict__ u,
                            const short* __restrict__ w3p,
                            const float* __restrict__ b3,
                            const short* __restrict__ w4p,
                            const float* __restrict__ b4,
                            const float* __restrict__ gamma,
                            const float* __restrict__ beta,
                            const int* __restrict__ batch,
                            const unsigned short* __restrict__ aggbf,
                            float* __restrict__ out) {
  __shared__ __align__(16) short smem[64 * 1024];
  const int tid = threadIdx.x;
  const int lane = tid & 63;
  const int w = tid >> 6;
  const int lh = lane >> 4;
  const int ll = lane & 15;
  const int n0 = blockIdx.x * 64;

  #pragma unroll
  for (int it = 0; it < 7; ++it) {
    int ch = tid + it * 512;
    int rr = ch / 56;
    int cc = (ch - rr * 56) * 8;
    s8v vals = {0, 0, 0, 0, 0, 0, 0, 0};
    int node = n0 + rr;
    if (node < NN) {
      if (cc < 256) {
        vals = *(const s8v*)(xbf + (size_t)node * ND + cc);
      } else if (cc < 384) {
        vals = *(const s8v*)(aggbf + (size_t)node * ED + (cc - 256));
      } else {
        const float* up = u + (size_t)batch[node] * GD + (cc - 384);
        const float4 v0 = *(const float4*)(up);
        const float4 v1 = *(const float4*)(up + 4);
        vals[0] = f2bf(v0.x); vals[1] = f2bf(v0.y); vals[2] = f2bf(v0.z); vals[3] = f2bf(v0.w);
        vals[4] = f2bf(v1.x); vals[5] = f2bf(v1.y); vals[6] = f2bf(v1.z); vals[7] = f2bf(v1.w);
      }
    }
    int byte = (rr * 896 + cc * 2) ^ ((rr & 7) << 4);
    *(s8v*)((char*)smem + byte) = vals;
  }
  __syncthreads();

  f4v acc3[8][4];
  #pragma unroll
  for (int n = 0; n < 8; ++n)
    #pragma unroll
    for (int m = 0; m < 4; ++m)
      acc3[n][m] = (f4v){0.f, 0.f, 0.f, 0.f};

  for (int ks = 0; ks < 14; ++ks) {
    s8v af[4];
    #pragma unroll
    for (int m = 0; m < 4; ++m) {
      int row = 16 * m + ll;
      int byte = (row * 896 + ks * 64 + lh * 16) ^ ((row & 7) << 4);
      af[m] = *(const s8v*)((const char*)smem + byte);
    }
    #pragma unroll
    for (int n = 0; n < 8; ++n) {
      s8v wf = *(const s8v*)(w3p + (((ks * 1024 + w * 128 + 16 * n + ll) * 4 + lh) << 3));
      #pragma unroll
      for (int m = 0; m < 4; ++m)
        acc3[n][m] = __builtin_amdgcn_mfma_f32_16x16x32_bf16(wf, af[m], acc3[n][m], 0, 0, 0);
    }
  }
  __syncthreads();

  #pragma unroll
  for (int n = 0; n < 8; ++n) {
    int cb = w * 128 + 16 * n + 4 * lh;
    const float4 bv = *(const float4*)(b3 + cb);
    #pragma unroll
    for (int m = 0; m < 4; ++m) {
      int row = 16 * m + ll;
      s4v o;
      float v0 = acc3[n][m][0] + bv.x; o[0] = f2bf(v0 > 0.f ? v0 : 0.f);
      float v1 = acc3[n][m][1] + bv.y; o[1] = f2bf(v1 > 0.f ? v1 : 0.f);
      float v2 = acc3[n][m][2] + bv.z; o[2] = f2bf(v2 > 0.f ? v2 : 0.f);
      float v3 = acc3[n][m][3] + bv.w; o[3] = f2bf(v3 > 0.f ? v3 : 0.f);
      int byte = (row * 2048 + cb * 2) ^ ((row & 7) << 4);
      *(s4v*)((char*)smem + byte) = o;
    }
  }
  __syncthreads();

  f4v acc4[2][4];
  #pragma unroll
  for (int n = 0; n < 2; ++n)
    #pragma unroll
    for (int m = 0; m < 4; ++m)
      acc4[n][m] = (f4v){0.f, 0.f, 0.f, 0.f};

  for (int ks = 0; ks < 32; ++ks) {
    s8v hf[4];
    #pragma unroll
    for (int m = 0; m < 4; ++m) {
      int row = 16 * m + ll;
      int byte = (row * 2048 + ks * 64 + lh * 16) ^ ((row & 7) << 4);
      hf[m] = *(const s8v*)((const char*)smem + byte);
    }
    #pragma unroll
    for (int n = 0; n < 2; ++n) {
      s8v wf = *(const s8v*)(w4p + (((ks * 256 + w * 32 + 16 * n + ll) * 4 + lh) << 3));
      #pragma unroll
      for (int m = 0; m < 4; ++m)
        acc4[n][m] = __builtin_amdgcn_mfma_f32_16x16x32_bf16(wf, hf[m], acc4[n][m], 0, 0, 0);
    }
  }
  __syncthreads();

  float* yb = (float*)smem;
  #pragma unroll
  for (int n = 0; n < 2; ++n) {
    int cb = w * 32 + 16 * n + 4 * lh;
    const float4 bv = *(const float4*)(b4 + cb);
    #pragma unroll
    for (int m = 0; m < 4; ++m) {
      int row = 16 * m + ll;
      int node = n0 + row;
      float4 xv = {0.f, 0.f, 0.f, 0.f};
      if (node < NN) xv = *(const float4*)(x + (size_t)node * ND + cb);
      f4v o;
      o[0] = acc4[n][m][0] + bv.x + xv.x;
      o[1] = acc4[n][m][1] + bv.y + xv.y;
      o[2] = acc4[n][m][2] + bv.z + xv.z;
      o[3] = acc4[n][m][3] + bv.w + xv.w;
      *(f4v*)(yb + row * 260 + cb) = o;
    }
  }
  __syncthreads();

  {
    int row = tid >> 3, sub = tid & 7;
    int node = n0 + row;
    float v[32];
    float sum = 0.f, ssq = 0.f;
    #pragma unroll
    for (int i = 0; i < 8; ++i) {
      const float4 t = *(const float4*)(yb + row * 260 + (i * 8 + sub) * 4);
      v[i * 4 + 0] = t.x; v[i * 4 + 1] = t.y; v[i * 4 + 2] = t.z; v[i * 4 + 3] = t.w;
      sum += t.x + t.y + t.z + t.w;
      ssq += t.x * t.x + t.y * t.y + t.z * t.z + t.w * t.w;
    }
    #pragma unroll
    for (int d = 1; d < 8; d <<= 1) {
      sum += __shfl_xor(sum, d);
      ssq += __shfl_xor(ssq, d);
    }
    float mu = sum * (1.f / 256.f);
    float var = ssq * (1.f / 256.f) - mu * mu;
    float rstd = rsqrtf(var + 1e-5f);
    if (node < NN) {
      #pragma unroll
      for (int i = 0; i < 8; ++i) {
        int c = (i * 8 + sub) * 4;
        const float4 g = *(const float4*)(gamma + c);
        const float4 be = *(const float4*)(beta + c);
        float4 o;
        o.x = (v[i * 4 + 0] - mu) * rstd * g.x + be.x;
        o.y = (v[i * 4 + 1] - mu) * rstd * g.y + be.y;
        o.z = (v[i * 4 + 2] - mu) * rstd * g.z + be.z;
        o.w = (v[i * 4 + 3] - mu) * rstd * g.w + be.w;
        *(float4*)(out + (size_t)node * ND + c) = o;
      }
    }
  }
}

extern "C" void kernel_launch(void* const* d_in, const int* in_sizes, int n_in,
                              void* d_out, int out_size, void* d_ws, size_t ws_size,
                              hipStream_t stream) {
  const float* x    = (const float*)d_in[0];
  const float* ea   = (const float*)d_in[1];
  const float* u    = (const float*)d_in[2];
  const float* W1   = (const float*)d_in[3];
  const float* b1   = (const float*)d_in[4];
  const float* W2   = (const float*)d_in[5];
  const float* b2   = (const float*)d_in[6];
  const float* W3   = (const float*)d_in[7];
  const float* b3   = (const float*)d_in[8];
  const float* W4   = (const float*)d_in[9];
  const float* b4   = (const float*)d_in[10];
  const float* gamma = (const float*)d_in[11];
  const float* beta  = (const float*)d_in[12];
  const int* eidx   = (const int*)d_in[13];
  const int* batch  = (const int*)d_in[14];
  float* out = (float*)d_out;

  char* p = (char*)d_ws;
  size_t off = 0;
  auto take = [&](size_t n) { char* r = p + off; off = (off + n + 255) & ~(size_t)255; return r; };
  short* xbf = (short*)take((size_t)NN * ND * 2);
  short* w1p = (short*)take((size_t)384 * 512 * 2);     // fallback full-K pack
  short* w2p = (short*)take((size_t)512 * 128 * 2);
  short* w3p = (short*)take((size_t)448 * 1024 * 2);
  short* w4p = (short*)take((size_t)1024 * 256 * 2);
  // contiguous counter region (one memset covers all three)
  size_t cnt_off = off;
  unsigned int* cnt  = (unsigned int*)take((size_t)NN * 4);
  unsigned int* rcnt = (unsigned int*)take((size_t)NN * 4);
  unsigned int* rcur = (unsigned int*)take((size_t)NN * 4);
  size_t cnt_span = off - cnt_off;
  int* elist = (int*)take((size_t)NN * MAXDEG * 4);
  unsigned short* aggbf = (unsigned short*)take((size_t)NN * ED * 2);
  unsigned short* ebuf = (unsigned short*)take((size_t)NE * ED * 2);
  // hx extras
  short* hxb  = (short*)take((size_t)NN * 512 * 2);
  short* w1xp = (short*)take((size_t)256 * 512 * 2);
  short* w1ep = (short*)take((size_t)128 * 512 * 2);
  // sort extras
  int* rbase = (int*)take((size_t)NN * 4);
  int* order = (int*)take((size_t)NE * 4);
  int* srow  = (int*)take((size_t)NE * 4);
  size_t need_sort = off;
  bool sortpath = ws_size >= need_sort;

  const int* erow = eidx;
  const int* ecol = eidx + NE;

  cvt_bf16_kernel<<<(NN * ND / 4 + 255) / 256, 256, 0, stream>>>(x, xbf, NN * ND);
  pack_w_kernel<<<(512 * 128 + 255) / 256, 256, 0, stream>>>(W2, w2p, 512, 128);
  pack_w_kernel<<<(448 * 1024 + 255) / 256, 256, 0, stream>>>(W3, w3p, 448, 1024);
  pack_w_kernel<<<(1024 * 256 + 255) / 256, 256, 0, stream>>>(W4, w4p, 1024, 256);
  hipMemsetAsync(p + cnt_off, 0, cnt_span, stream);

  if (sortpath) {
    pack_w_kernel<<<(256 * 512 + 255) / 256, 256, 0, stream>>>(W1, w1xp, 256, 512);
    pack_w_kernel<<<(128 * 512 + 255) / 256, 256, 0, stream>>>(W1 + 256 * 512, w1ep, 128, 512);
    hist_kernel<<<(NE + 255) / 256, 256, 0, stream>>>(erow, rcnt);
    scan_kernel<<<1, 1024, 0, stream>>>(rcnt, rbase);
    scatter_build_kernel<<<(NE + 255) / 256, 256, 0, stream>>>(erow, ecol, rbase, rcur,
                                                               order, srow, cnt, elist);
    hx_kernel<<<(NN + 63) / 64, 512, 0, stream>>>(xbf, w1xp, hxb);
    edge_kernel<2><<<(NE + 63) / 64, 512, 0, stream>>>(xbf, hxb, ea, w1ep, b1, w2p, b2,
                                                       erow, order, srow, ebuf);
  } else {
    pack_w_kernel<<<(384 * 512 + 255) / 256, 256, 0, stream>>>(W1, w1p, 384, 512);
    build_kernel<<<(NE + 255) / 256, 256, 0, stream>>>(ecol, cnt, elist);
    edge_kernel<0><<<(NE + 63) / 64, 512, 0, stream>>>(xbf, nullptr, ea, w1p, b1, w2p, b2,
                                                       erow, nullptr, nullptr, ebuf);
  }
  agg_kernel<<<(NN + 3) / 4, 256, 0, stream>>>(ebuf, elist, cnt, aggbf);
  node_kernel<<<(NN + 63) / 64, 512, 0, stream>>>(x, xbf, u, w3p, b3, w4p, b4,
                                                  gamma, beta, batch, aggbf, out);
}

// Round 7
// 912.167 us; speedup vs baseline: 1.0160x; 1.0160x over previous
//
#include <hip/hip_runtime.h>
#include <stdint.h>

#define NE 500000
#define NN 50000
#define ND 256
#define ED 128
#define GD 64
#define MAXDEG 64

typedef float f4v __attribute__((ext_vector_type(4)));
typedef short s8v __attribute__((ext_vector_type(8)));
typedef short s4v __attribute__((ext_vector_type(4)));

static __device__ __forceinline__ short f2bf(float f) {
  union { float f; uint32_t u; } v; v.f = f;
  uint32_t r = v.u + 0x7FFFu + ((v.u >> 16) & 1u);
  return (short)(r >> 16);
}
static __device__ __forceinline__ float bf2f(uint32_t u) {
  union { uint32_t u; float f; } v; v.u = u << 16; return v.f;
}

// ---- convert fp32 -> bf16 (vectorized x4) ----
__global__ void cvt_bf16_kernel(const float* __restrict__ src, short* __restrict__ dst, int n) {
  int i = (blockIdx.x * blockDim.x + threadIdx.x) * 4;
  if (i >= n) return;
  const float4 v = *(const float4*)(src + i);
  s4v o; o[0] = f2bf(v.x); o[1] = f2bf(v.y); o[2] = f2bf(v.z); o[3] = f2bf(v.w);
  *(s4v*)(dst + i) = o;
}

// ---- pack W[K][C] row-major fp32 -> bf16 MFMA fragment order [ks][c][kh][j] ----
__global__ void pack_w_kernel(const float* __restrict__ src, short* __restrict__ dst, int K, int C) {
  int idx = blockIdx.x * blockDim.x + threadIdx.x;
  if (idx >= K * C) return;
  int k = idx / C, c = idx - k * C;
  int ks = k >> 5, kh = (k >> 3) & 3, j = k & 7;
  dst[(((ks * C + c) * 4 + kh) << 3) + j] = f2bf(src[idx]);
}

// ---- build per-destination lists over raw edge ids ----
__global__ void build_kernel(const int* __restrict__ ecol, unsigned int* __restrict__ cnt,
                             int* __restrict__ elist) {
  int e = blockIdx.x * blockDim.x + threadIdx.x;
  if (e >= NE) return;
  int c = ecol[e];
  unsigned int slot = atomicAdd(&cnt[c], 1u);
  if (slot < MAXDEG) elist[c * MAXDEG + slot] = e;
}

// ---- gather-mean: one wave per node, lane handles 2 dims ----
__global__ void agg_kernel(const unsigned short* __restrict__ ebuf,
                           const int* __restrict__ elist,
                           const unsigned int* __restrict__ cnt,
                           unsigned short* __restrict__ aggbf) {
  int tid = threadIdx.x;
  int lane = tid & 63;
  int node = blockIdx.x * 4 + (tid >> 6);
  if (node >= NN) return;
  unsigned int deg = cnt[node];
  unsigned int jend = deg < MAXDEG ? deg : MAXDEG;
  float a0 = 0.f, a1 = 0.f;
  const int* el = elist + (size_t)node * MAXDEG;
  for (unsigned int j = 0; j < jend; ++j) {
    int eid = el[j];
    uint32_t v = *(const uint32_t*)(ebuf + (size_t)eid * ED + 2 * lane);
    a0 += bf2f(v & 0xFFFFu);
    a1 += bf2f(v >> 16);
  }
  float rc = 1.0f / (deg > 0 ? (float)deg : 1.0f);
  uint32_t o = (uint32_t)(uint16_t)f2bf(a0 * rc) | ((uint32_t)(uint16_t)f2bf(a1 * rc) << 16);
  *(uint32_t*)(aggbf + (size_t)node * ED + 2 * lane) = o;
}

// =======================================================================
// Edge kernel: M=32 edges/WG, 8 waves (512 thr), operand-swapped MFMA.
// GEMM1 [32x384]@[384x512] with acc1[4][2] (wave w owns cols {w*32..+32}
// of each 256-half), H1 written in two 256-col halves (16KB LDS), GEMM2
// K=512 done as two K=256 passes. LDS = A1 24KB + H1half 16KB ~= 41KB
// -> 3 blocks/CU = 24 waves (vs 16 in R3).  Output staged in LDS then
// stored fully coalesced (16B/thread).
// =======================================================================
__launch_bounds__(512, 6)
__global__ void edge_kernel(const short* __restrict__ xbf,
                            const float* __restrict__ edge_attr,
                            const short* __restrict__ w1p,
                            const float* __restrict__ b1,
                            const short* __restrict__ w2p,
                            const float* __restrict__ b2,
                            const int* __restrict__ erow,
                            unsigned short* __restrict__ ebuf) {
  // region0: A1 [32][384] bf16 (24KB), later out-tile [32][128] (8KB)
  // region1: H1 half [32][256] bf16 (16KB)
  __shared__ __align__(16) short smem[(32 * 384) + (32 * 256)];
  __shared__ int rid[32];
  const int tid = threadIdx.x;
  const int lane = tid & 63;
  const int w = tid >> 6;          // wave 0..7
  const int lh = lane >> 4;        // 0..3
  const int ll = lane & 15;        // 0..15
  const int e0 = blockIdx.x * 32;
  char* const h1b = (char*)smem + 32 * 384 * 2;   // H1 half base

  if (tid < 32) {
    int e = e0 + tid;
    rid[tid] = (e < NE) ? erow[e] : 0;
  }
  __syncthreads();

  // ---- stage A1 [32][384] bf16, XOR-swizzled rows (3 iters) ----
  #pragma unroll
  for (int it = 0; it < 3; ++it) {
    int ch = tid + it * 512;             // 1536 chunks of 8 elems
    int rr = ch / 48;
    int cc = (ch - rr * 48) * 8;
    s8v vals = {0, 0, 0, 0, 0, 0, 0, 0};
    if (e0 + rr < NE) {
      if (cc < ND) {
        vals = *(const s8v*)(xbf + (size_t)rid[rr] * ND + cc);
      } else {
        const float* p = edge_attr + (size_t)(e0 + rr) * ED + (cc - ND);
        const float4 v0 = *(const float4*)(p);
        const float4 v1 = *(const float4*)(p + 4);
        vals[0] = f2bf(v0.x); vals[1] = f2bf(v0.y); vals[2] = f2bf(v0.z); vals[3] = f2bf(v0.w);
        vals[4] = f2bf(v1.x); vals[5] = f2bf(v1.y); vals[6] = f2bf(v1.z); vals[7] = f2bf(v1.w);
      }
    }
    int byte = (rr * 768 + cc * 2) ^ ((rr & 7) << 4);
    *(s8v*)((char*)smem + byte) = vals;
  }
  __syncthreads();

  // ---- GEMM1 (swapped): acc1[n][m]; wave w cols: n<2 -> w*32+16n (half A),
  //      n>=2 -> 256 + w*32 + 16(n-2) (half B); edges 16m+ll ----
  f4v acc1[4][2];
  #pragma unroll
  for (int n = 0; n < 4; ++n)
    #pragma unroll
    for (int m = 0; m < 2; ++m)
      acc1[n][m] = (f4v){0.f, 0.f, 0.f, 0.f};

  for (int ks = 0; ks < 12; ++ks) {
    s8v hf[2];
    #pragma unroll
    for (int m = 0; m < 2; ++m) {
      int row = 16 * m + ll;
      int byte = (row * 768 + ks * 64 + lh * 16) ^ ((row & 7) << 4);
      hf[m] = *(const s8v*)((const char*)smem + byte);
    }
    #pragma unroll
    for (int n = 0; n < 4; ++n) {
      int nc = (n < 2) ? (w * 32 + 16 * n) : (256 + w * 32 + 16 * (n - 2));
      s8v wf = *(const s8v*)(w1p + (((ks * 512 + nc + ll) * 4 + lh) << 3));
      #pragma unroll
      for (int m = 0; m < 2; ++m)
        acc1[n][m] = __builtin_amdgcn_mfma_f32_16x16x32_bf16(wf, hf[m], acc1[n][m], 0, 0, 0);
    }
  }

  f4v acc2[2];
  acc2[0] = (f4v){0.f, 0.f, 0.f, 0.f};
  acc2[1] = (f4v){0.f, 0.f, 0.f, 0.f};

  // ---- two half passes: write H1 half -> GEMM2 over its K=256 ----
  #pragma unroll
  for (int half = 0; half < 2; ++half) {
    __syncthreads();   // H1 buffer free (prev GEMM2 reads done / first entry)
    #pragma unroll
    for (int nn = 0; nn < 2; ++nn) {
      int n = half * 2 + nn;
      int hcb = w * 32 + 16 * nn + 4 * lh;        // local col in [0,256)
      const float4 bv = *(const float4*)(b1 + half * 256 + hcb);
      #pragma unroll
      for (int m = 0; m < 2; ++m) {
        int row = 16 * m + ll;
        s4v o;
        float v0 = acc1[n][m][0] + bv.x; o[0] = f2bf(v0 > 0.f ? v0 : 0.f);
        float v1 = acc1[n][m][1] + bv.y; o[1] = f2bf(v1 > 0.f ? v1 : 0.f);
        float v2 = acc1[n][m][2] + bv.z; o[2] = f2bf(v2 > 0.f ? v2 : 0.f);
        float v3 = acc1[n][m][3] + bv.w; o[3] = f2bf(v3 > 0.f ? v3 : 0.f);
        int byte = (row * 512 + hcb * 2) ^ ((row & 7) << 4);
        *(s4v*)(h1b + byte) = o;
      }
    }
    __syncthreads();   // H1 half visible

    for (int ksl = 0; ksl < 8; ++ksl) {
      int ksg = half * 8 + ksl;
      s8v wf = *(const s8v*)(w2p + (((ksg * 128 + w * 16 + ll) * 4 + lh) << 3));
      #pragma unroll
      for (int m = 0; m < 2; ++m) {
        int row = 16 * m + ll;
        int byte = (row * 512 + ksl * 64 + lh * 16) ^ ((row & 7) << 4);
        s8v hf = *(const s8v*)(h1b + byte);
        acc2[m] = __builtin_amdgcn_mfma_f32_16x16x32_bf16(wf, hf, acc2[m], 0, 0, 0);
      }
    }
  }
  __syncthreads();   // all A1/H1 reads done; reuse region0 for out tile

  // ---- stage output tile [32][128] bf16 (swizzled) ----
  {
    int cb = w * 16 + 4 * lh;
    const float4 bv = *(const float4*)(b2 + cb);
    #pragma unroll
    for (int m = 0; m < 2; ++m) {
      int row = 16 * m + ll;
      s4v o;
      o[0] = f2bf(acc2[m][0] + bv.x);
      o[1] = f2bf(acc2[m][1] + bv.y);
      o[2] = f2bf(acc2[m][2] + bv.z);
      o[3] = f2bf(acc2[m][3] + bv.w);
      int byte = (row * 256 + cb * 2) ^ ((row & 7) << 4);
      *(s4v*)((char*)smem + byte) = o;
    }
  }
  __syncthreads();

  // ---- coalesced store: 512 threads x 16B = full 8KB tile ----
  {
    size_t g0 = (size_t)e0 * ED;        // elements
    int B = tid * 16;                   // byte offset in [0,8192)
    int row = B >> 8;
    int lb = B ^ ((row & 7) << 4);
    s8v v = *(const s8v*)((const char*)smem + lb);
    if (e0 + row < NE)
      *(s8v*)((char*)(ebuf + g0) + B) = v;
  }
}

// =======================================================================
// Node kernel: unchanged (R3 form).
// =======================================================================
__launch_bounds__(512, 2)
__global__ void node_kernel(const float* __restrict__ x,
                            const short* __restrict__ xbf,
                            const float* __restrict__ u,
                            const short* __restrict__ w3p,
                            const float* __restrict__ b3,
                            const short* __restrict__ w4p,
                            const float* __restrict__ b4,
                            const float* __restrict__ gamma,
                            const float* __restrict__ beta,
                            const int* __restrict__ batch,
                            const unsigned short* __restrict__ aggbf,
                            float* __restrict__ out) {
  __shared__ __align__(16) short smem[64 * 1024];
  const int tid = threadIdx.x;
  const int lane = tid & 63;
  const int w = tid >> 6;
  const int lh = lane >> 4;
  const int ll = lane & 15;
  const int n0 = blockIdx.x * 64;

  #pragma unroll
  for (int it = 0; it < 7; ++it) {
    int ch = tid + it * 512;
    int rr = ch / 56;
    int cc = (ch - rr * 56) * 8;
    s8v vals = {0, 0, 0, 0, 0, 0, 0, 0};
    int node = n0 + rr;
    if (node < NN) {
      if (cc < 256) {
        vals = *(const s8v*)(xbf + (size_t)node * ND + cc);
      } else if (cc < 384) {
        vals = *(const s8v*)(aggbf + (size_t)node * ED + (cc - 256));
      } else {
        const float* up = u + (size_t)batch[node] * GD + (cc - 384);
        const float4 v0 = *(const float4*)(up);
        const float4 v1 = *(const float4*)(up + 4);
        vals[0] = f2bf(v0.x); vals[1] = f2bf(v0.y); vals[2] = f2bf(v0.z); vals[3] = f2bf(v0.w);
        vals[4] = f2bf(v1.x); vals[5] = f2bf(v1.y); vals[6] = f2bf(v1.z); vals[7] = f2bf(v1.w);
      }
    }
    int byte = (rr * 896 + cc * 2) ^ ((rr & 7) << 4);
    *(s8v*)((char*)smem + byte) = vals;
  }
  __syncthreads();

  f4v acc3[8][4];
  #pragma unroll
  for (int n = 0; n < 8; ++n)
    #pragma unroll
    for (int m = 0; m < 4; ++m)
      acc3[n][m] = (f4v){0.f, 0.f, 0.f, 0.f};

  for (int ks = 0; ks < 14; ++ks) {
    s8v af[4];
    #pragma unroll
    for (int m = 0; m < 4; ++m) {
      int row = 16 * m + ll;
      int byte = (row * 896 + ks * 64 + lh * 16) ^ ((row & 7) << 4);
      af[m] = *(const s8v*)((const char*)smem + byte);
    }
    #pragma unroll
    for (int n = 0; n < 8; ++n) {
      s8v wf = *(const s8v*)(w3p + (((ks * 1024 + w * 128 + 16 * n + ll) * 4 + lh) << 3));
      #pragma unroll
      for (int m = 0; m < 4; ++m)
        acc3[n][m] = __builtin_amdgcn_mfma_f32_16x16x32_bf16(wf, af[m], acc3[n][m], 0, 0, 0);
    }
  }
  __syncthreads();

  #pragma unroll
  for (int n = 0; n < 8; ++n) {
    int cb = w * 128 + 16 * n + 4 * lh;
    const float4 bv = *(const float4*)(b3 + cb);
    #pragma unroll
    for (int m = 0; m < 4; ++m) {
      int row = 16 * m + ll;
      s4v o;
      float v0 = acc3[n][m][0] + bv.x; o[0] = f2bf(v0 > 0.f ? v0 : 0.f);
      float v1 = acc3[n][m][1] + bv.y; o[1] = f2bf(v1 > 0.f ? v1 : 0.f);
      float v2 = acc3[n][m][2] + bv.z; o[2] = f2bf(v2 > 0.f ? v2 : 0.f);
      float v3 = acc3[n][m][3] + bv.w; o[3] = f2bf(v3 > 0.f ? v3 : 0.f);
      int byte = (row * 2048 + cb * 2) ^ ((row & 7) << 4);
      *(s4v*)((char*)smem + byte) = o;
    }
  }
  __syncthreads();

  f4v acc4[2][4];
  #pragma unroll
  for (int n = 0; n < 2; ++n)
    #pragma unroll
    for (int m = 0; m < 4; ++m)
      acc4[n][m] = (f4v){0.f, 0.f, 0.f, 0.f};

  for (int ks = 0; ks < 32; ++ks) {
    s8v hf[4];
    #pragma unroll
    for (int m = 0; m < 4; ++m) {
      int row = 16 * m + ll;
      int byte = (row * 2048 + ks * 64 + lh * 16) ^ ((row & 7) << 4);
      hf[m] = *(const s8v*)((const char*)smem + byte);
    }
    #pragma unroll
    for (int n = 0; n < 2; ++n) {
      s8v wf = *(const s8v*)(w4p + (((ks * 256 + w * 32 + 16 * n + ll) * 4 + lh) << 3));
      #pragma unroll
      for (int m = 0; m < 4; ++m)
        acc4[n][m] = __builtin_amdgcn_mfma_f32_16x16x32_bf16(wf, hf[m], acc4[n][m], 0, 0, 0);
    }
  }
  __syncthreads();

  float* yb = (float*)smem;
  #pragma unroll
  for (int n = 0; n < 2; ++n) {
    int cb = w * 32 + 16 * n + 4 * lh;
    const float4 bv = *(const float4*)(b4 + cb);
    #pragma unroll
    for (int m = 0; m < 4; ++m) {
      int row = 16 * m + ll;
      int node = n0 + row;
      float4 xv = {0.f, 0.f, 0.f, 0.f};
      if (node < NN) xv = *(const float4*)(x + (size_t)node * ND + cb);
      f4v o;
      o[0] = acc4[n][m][0] + bv.x + xv.x;
      o[1] = acc4[n][m][1] + bv.y + xv.y;
      o[2] = acc4[n][m][2] + bv.z + xv.z;
      o[3] = acc4[n][m][3] + bv.w + xv.w;
      *(f4v*)(yb + row * 260 + cb) = o;
    }
  }
  __syncthreads();

  {
    int row = tid >> 3, sub = tid & 7;
    int node = n0 + row;
    float v[32];
    float sum = 0.f, ssq = 0.f;
    #pragma unroll
    for (int i = 0; i < 8; ++i) {
      const float4 t = *(const float4*)(yb + row * 260 + (i * 8 + sub) * 4);
      v[i * 4 + 0] = t.x; v[i * 4 + 1] = t.y; v[i * 4 + 2] = t.z; v[i * 4 + 3] = t.w;
      sum += t.x + t.y + t.z + t.w;
      ssq += t.x * t.x + t.y * t.y + t.z * t.z + t.w * t.w;
    }
    #pragma unroll
    for (int d = 1; d < 8; d <<= 1) {
      sum += __shfl_xor(sum, d);
      ssq += __shfl_xor(ssq, d);
    }
    float mu = sum * (1.f / 256.f);
    float var = ssq * (1.f / 256.f) - mu * mu;
    float rstd = rsqrtf(var + 1e-5f);
    if (node < NN) {
      #pragma unroll
      for (int i = 0; i < 8; ++i) {
        int c = (i * 8 + sub) * 4;
        const float4 g = *(const float4*)(gamma + c);
        const float4 be = *(const float4*)(beta + c);
        float4 o;
        o.x = (v[i * 4 + 0] - mu) * rstd * g.x + be.x;
        o.y = (v[i * 4 + 1] - mu) * rstd * g.y + be.y;
        o.z = (v[i * 4 + 2] - mu) * rstd * g.z + be.z;
        o.w = (v[i * 4 + 3] - mu) * rstd * g.w + be.w;
        *(float4*)(out + (size_t)node * ND + c) = o;
      }
    }
  }
}

extern "C" void kernel_launch(void* const* d_in, const int* in_sizes, int n_in,
                              void* d_out, int out_size, void* d_ws, size_t ws_size,
                              hipStream_t stream) {
  const float* x    = (const float*)d_in[0];
  const float* ea   = (const float*)d_in[1];
  const float* u    = (const float*)d_in[2];
  const float* W1   = (const float*)d_in[3];
  const float* b1   = (const float*)d_in[4];
  const float* W2   = (const float*)d_in[5];
  const float* b2   = (const float*)d_in[6];
  const float* W3   = (const float*)d_in[7];
  const float* b3   = (const float*)d_in[8];
  const float* W4   = (const float*)d_in[9];
  const float* b4   = (const float*)d_in[10];
  const float* gamma = (const float*)d_in[11];
  const float* beta  = (const float*)d_in[12];
  const int* eidx   = (const int*)d_in[13];
  const int* batch  = (const int*)d_in[14];
  float* out = (float*)d_out;

  char* p = (char*)d_ws;
  size_t off = 0;
  auto take = [&](size_t n) { char* r = p + off; off = (off + n + 255) & ~(size_t)255; return r; };
  short* xbf = (short*)take((size_t)NN * ND * 2);
  short* w1p = (short*)take((size_t)384 * 512 * 2);
  short* w2p = (short*)take((size_t)512 * 128 * 2);
  short* w3p = (short*)take((size_t)448 * 1024 * 2);
  short* w4p = (short*)take((size_t)1024 * 256 * 2);
  unsigned int* cnt = (unsigned int*)take((size_t)NN * 4);
  int* elist = (int*)take((size_t)NN * MAXDEG * 4);
  unsigned short* aggbf = (unsigned short*)take((size_t)NN * ED * 2);
  unsigned short* ebuf = (unsigned short*)take((size_t)NE * ED * 2);

  const int* erow = eidx;
  const int* ecol = eidx + NE;

  cvt_bf16_kernel<<<(NN * ND / 4 + 255) / 256, 256, 0, stream>>>(x, xbf, NN * ND);
  pack_w_kernel<<<(384 * 512 + 255) / 256, 256, 0, stream>>>(W1, w1p, 384, 512);
  pack_w_kernel<<<(512 * 128 + 255) / 256, 256, 0, stream>>>(W2, w2p, 512, 128);
  pack_w_kernel<<<(448 * 1024 + 255) / 256, 256, 0, stream>>>(W3, w3p, 448, 1024);
  pack_w_kernel<<<(1024 * 256 + 255) / 256, 256, 0, stream>>>(W4, w4p, 1024, 256);
  hipMemsetAsync(cnt, 0, (size_t)NN * 4, stream);
  build_kernel<<<(NE + 255) / 256, 256, 0, stream>>>(ecol, cnt, elist);

  edge_kernel<<<(NE + 31) / 32, 512, 0, stream>>>(xbf, ea, w1p, b1, w2p, b2, erow, ebuf);
  agg_kernel<<<(NN + 3) / 4, 256, 0, stream>>>(ebuf, elist, cnt, aggbf);
  node_kernel<<<(NN + 63) / 64, 512, 0, stream>>>(x, xbf, u, w3p, b3, w4p, b4,
                                                  gamma, beta, batch, aggbf, out);
}

// Round 8
// 738.467 us; speedup vs baseline: 1.2549x; 1.2352x over previous
//
#include <hip/hip_runtime.h>
#include <stdint.h>

#define NE 500000
#define NN 50000
#define ND 256
#define ED 128
#define GD 64
#define MAXDEG 64

typedef float f4v __attribute__((ext_vector_type(4)));
typedef short s8v __attribute__((ext_vector_type(8)));
typedef short s4v __attribute__((ext_vector_type(4)));

static __device__ __forceinline__ short f2bf(float f) {
  union { float f; uint32_t u; } v; v.f = f;
  uint32_t r = v.u + 0x7FFFu + ((v.u >> 16) & 1u);
  return (short)(r >> 16);
}
static __device__ __forceinline__ float bf2f(uint32_t u) {
  union { uint32_t u; float f; } v; v.u = u << 16; return v.f;
}

// ---- convert fp32 -> bf16 (vectorized x4) ----
__global__ void cvt_bf16_kernel(const float* __restrict__ src, short* __restrict__ dst, int n) {
  int i = (blockIdx.x * blockDim.x + threadIdx.x) * 4;
  if (i >= n) return;
  const float4 v = *(const float4*)(src + i);
  s4v o; o[0] = f2bf(v.x); o[1] = f2bf(v.y); o[2] = f2bf(v.z); o[3] = f2bf(v.w);
  *(s4v*)(dst + i) = o;
}

// ---- pack W[K][C] row-major fp32 -> bf16 MFMA fragment order [ks][c][kh][j] ----
__global__ void pack_w_kernel(const float* __restrict__ src, short* __restrict__ dst, int K, int C) {
  int idx = blockIdx.x * blockDim.x + threadIdx.x;
  if (idx >= K * C) return;
  int k = idx / C, c = idx - k * C;
  int ks = k >> 5, kh = (k >> 3) & 3, j = k & 7;
  dst[(((ks * C + c) * 4 + kh) << 3) + j] = f2bf(src[idx]);
}

// ---- build per-destination lists over raw edge ids ----
__global__ void build_kernel(const int* __restrict__ ecol, unsigned int* __restrict__ cnt,
                             int* __restrict__ elist) {
  int e = blockIdx.x * blockDim.x + threadIdx.x;
  if (e >= NE) return;
  int c = ecol[e];
  unsigned int slot = atomicAdd(&cnt[c], 1u);
  if (slot < MAXDEG) elist[c * MAXDEG + slot] = e;
}

// ---- gather-mean: one wave per node, lane handles 2 dims ----
__global__ void agg_kernel(const unsigned short* __restrict__ ebuf,
                           const int* __restrict__ elist,
                           const unsigned int* __restrict__ cnt,
                           unsigned short* __restrict__ aggbf) {
  int tid = threadIdx.x;
  int lane = tid & 63;
  int node = blockIdx.x * 4 + (tid >> 6);
  if (node >= NN) return;
  unsigned int deg = cnt[node];
  unsigned int jend = deg < MAXDEG ? deg : MAXDEG;
  float a0 = 0.f, a1 = 0.f;
  const int* el = elist + (size_t)node * MAXDEG;
  for (unsigned int j = 0; j < jend; ++j) {
    int eid = el[j];
    uint32_t v = *(const uint32_t*)(ebuf + (size_t)eid * ED + 2 * lane);
    a0 += bf2f(v & 0xFFFFu);
    a1 += bf2f(v >> 16);
  }
  float rc = 1.0f / (deg > 0 ? (float)deg : 1.0f);
  uint32_t o = (uint32_t)(uint16_t)f2bf(a0 * rc) | ((uint32_t)(uint16_t)f2bf(a1 * rc) << 16);
  *(uint32_t*)(aggbf + (size_t)node * ED + 2 * lane) = o;
}

// =======================================================================
// Edge kernel: M=128 edges/WG, 16 waves (1024 thr), operand-swapped MFMA.
// Rationale: each block pulls W1+W2 (512KB) through the CU<->L2 interface
// read-once; per-CU L2 BW (~140 GB/s) caps MfmaUtil at ~25% for M=64.
// M=128 halves weight-bytes/edge -> cap ~55%.
// LDS: A1 [128][384] (96KB, reused as out-tile) + H1-half [128][256]
// (64KB) = 160KB exactly (1 block/CU, 16 waves). rid lives in the H1
// region during staging (dead before first H1 write).
// GEMM1: wave w owns col-tile w (half0) and 16+w (half1): acc1[2][8].
// GEMM2: two K=256 passes; wave w owns c2-tile (w&7), edge-quarter (w>>3).
// =======================================================================
__launch_bounds__(1024, 4)
__global__ void edge_kernel(const short* __restrict__ xbf,
                            const float* __restrict__ edge_attr,
                            const short* __restrict__ w1p,
                            const float* __restrict__ b1,
                            const short* __restrict__ w2p,
                            const float* __restrict__ b2,
                            const int* __restrict__ erow,
                            unsigned short* __restrict__ ebuf) {
  __shared__ __align__(16) short smem[128 * 384 + 128 * 256];  // 96KB + 64KB
  char* const h1b = (char*)smem + 128 * 384 * 2;               // H1 half region
  int* const rid = (int*)h1b;                                  // transient: dead before H1 writes
  const int tid = threadIdx.x;
  const int lane = tid & 63;
  const int w = tid >> 6;          // wave 0..15
  const int lh = lane >> 4;        // 0..3
  const int ll = lane & 15;        // 0..15
  const int e0 = blockIdx.x * 128;

  if (tid < 128) {
    int e = e0 + tid;
    rid[tid] = (e < NE) ? erow[e] : 0;
  }
  __syncthreads();

  // ---- stage A1 [128][384] bf16, XOR-swizzled rows (6 iters) ----
  #pragma unroll
  for (int it = 0; it < 6; ++it) {
    int ch = tid + it * 1024;            // 6144 chunks of 8 elems
    int rr = ch / 48;
    int cc = (ch - rr * 48) * 8;
    s8v vals = {0, 0, 0, 0, 0, 0, 0, 0};
    if (e0 + rr < NE) {
      if (cc < ND) {
        vals = *(const s8v*)(xbf + (size_t)rid[rr] * ND + cc);
      } else {
        const float* p = edge_attr + (size_t)(e0 + rr) * ED + (cc - ND);
        const float4 v0 = *(const float4*)(p);
        const float4 v1 = *(const float4*)(p + 4);
        vals[0] = f2bf(v0.x); vals[1] = f2bf(v0.y); vals[2] = f2bf(v0.z); vals[3] = f2bf(v0.w);
        vals[4] = f2bf(v1.x); vals[5] = f2bf(v1.y); vals[6] = f2bf(v1.z); vals[7] = f2bf(v1.w);
      }
    }
    int byte = (rr * 768 + cc * 2) ^ ((rr & 7) << 4);
    *(s8v*)((char*)smem + byte) = vals;
  }
  __syncthreads();

  // ---- GEMM1 (swapped): acc1[n][mt]; n=0 -> col-tile w (cols 16w),
  //      n=1 -> col-tile 16+w (cols 256+16w); mt = edge-tile 0..7 ----
  f4v acc1[2][8];
  #pragma unroll
  for (int n = 0; n < 2; ++n)
    #pragma unroll
    for (int m = 0; m < 8; ++m)
      acc1[n][m] = (f4v){0.f, 0.f, 0.f, 0.f};

  for (int ks = 0; ks < 12; ++ks) {
    s8v wf0 = *(const s8v*)(w1p + (((ks * 512 + w * 16 + ll) * 4 + lh) << 3));
    s8v wf1 = *(const s8v*)(w1p + (((ks * 512 + 256 + w * 16 + ll) * 4 + lh) << 3));
    #pragma unroll
    for (int mh = 0; mh < 2; ++mh) {
      s8v hf[4];
      #pragma unroll
      for (int m = 0; m < 4; ++m) {
        int row = 64 * mh + 16 * m + ll;
        int byte = (row * 768 + ks * 64 + lh * 16) ^ ((row & 7) << 4);
        hf[m] = *(const s8v*)((const char*)smem + byte);
      }
      #pragma unroll
      for (int m = 0; m < 4; ++m) {
        acc1[0][4 * mh + m] = __builtin_amdgcn_mfma_f32_16x16x32_bf16(wf0, hf[m], acc1[0][4 * mh + m], 0, 0, 0);
        acc1[1][4 * mh + m] = __builtin_amdgcn_mfma_f32_16x16x32_bf16(wf1, hf[m], acc1[1][4 * mh + m], 0, 0, 0);
      }
    }
  }
  __syncthreads();   // A1 reads done for GEMM1; rid dead from here

  // ---- GEMM2 accumulators: c2-tile (w&7), edge-quarter (w>>3) ----
  f4v acc2[4];
  #pragma unroll
  for (int m = 0; m < 4; ++m)
    acc2[m] = (f4v){0.f, 0.f, 0.f, 0.f};

  // ---- two half passes over H1 cols: write half -> GEMM2 K=256 ----
  #pragma unroll
  for (int half = 0; half < 2; ++half) {
    // write H1 half: wave w writes its col-tile (local cols 16w+4lh..+3)
    {
      int lcb = w * 16 + 4 * lh;                    // local col in [0,256)
      const float4 bv = *(const float4*)(b1 + half * 256 + lcb);
      #pragma unroll
      for (int m = 0; m < 8; ++m) {
        int row = 16 * m + ll;
        s4v o;
        float v0 = acc1[half][m][0] + bv.x; o[0] = f2bf(v0 > 0.f ? v0 : 0.f);
        float v1 = acc1[half][m][1] + bv.y; o[1] = f2bf(v1 > 0.f ? v1 : 0.f);
        float v2 = acc1[half][m][2] + bv.z; o[2] = f2bf(v2 > 0.f ? v2 : 0.f);
        float v3 = acc1[half][m][3] + bv.w; o[3] = f2bf(v3 > 0.f ? v3 : 0.f);
        int byte = (row * 512 + lcb * 2) ^ ((row & 7) << 4);
        *(s4v*)(h1b + byte) = o;
      }
    }
    __syncthreads();   // H1 half visible

    // GEMM2 partial: K = 256 (8 ks)
    for (int ksl = 0; ksl < 8; ++ksl) {
      int ksg = half * 8 + ksl;
      s8v wf = *(const s8v*)(w2p + (((ksg * 128 + (w & 7) * 16 + ll) * 4 + lh) << 3));
      #pragma unroll
      for (int m = 0; m < 4; ++m) {
        int row = 64 * (w >> 3) + 16 * m + ll;
        int byte = (row * 512 + ksl * 64 + lh * 16) ^ ((row & 7) << 4);
        s8v hf = *(const s8v*)(h1b + byte);
        acc2[m] = __builtin_amdgcn_mfma_f32_16x16x32_bf16(wf, hf, acc2[m], 0, 0, 0);
      }
    }
    __syncthreads();   // all GEMM2 reads of this half done before overwrite
  }

  // ---- stage output tile [128][128] bf16 in A1 region (swizzled) ----
  {
    int cb = (w & 7) * 16 + 4 * lh;
    const float4 bv = *(const float4*)(b2 + cb);
    #pragma unroll
    for (int m = 0; m < 4; ++m) {
      int row = 64 * (w >> 3) + 16 * m + ll;
      s4v o;
      o[0] = f2bf(acc2[m][0] + bv.x);
      o[1] = f2bf(acc2[m][1] + bv.y);
      o[2] = f2bf(acc2[m][2] + bv.z);
      o[3] = f2bf(acc2[m][3] + bv.w);
      int byte = (row * 256 + cb * 2) ^ ((row & 7) << 4);
      *(s4v*)((char*)smem + byte) = o;
    }
  }
  __syncthreads();

  // ---- coalesced store: 1024 threads x 2 x 16B = full 32KB tile ----
  {
    size_t g0 = (size_t)e0 * ED;        // elements
    #pragma unroll
    for (int it = 0; it < 2; ++it) {
      int B = (tid + it * 1024) * 16;   // byte offset in [0,32768)
      int row = B >> 8;
      int lb = B ^ ((row & 7) << 4);
      s8v v = *(const s8v*)((const char*)smem + lb);
      if (e0 + row < NE)
        *(s8v*)((char*)(ebuf + g0) + B) = v;
    }
  }
}

// =======================================================================
// Node kernel: unchanged (R3 form).
// =======================================================================
__launch_bounds__(512, 2)
__global__ void node_kernel(const float* __restrict__ x,
                            const short* __restrict__ xbf,
                            const float* __restrict__ u,
                            const short* __restrict__ w3p,
                            const float* __restrict__ b3,
                            const short* __restrict__ w4p,
                            const float* __restrict__ b4,
                            const float* __restrict__ gamma,
                            const float* __restrict__ beta,
                            const int* __restrict__ batch,
                            const unsigned short* __restrict__ aggbf,
                            float* __restrict__ out) {
  __shared__ __align__(16) short smem[64 * 1024];
  const int tid = threadIdx.x;
  const int lane = tid & 63;
  const int w = tid >> 6;
  const int lh = lane >> 4;
  const int ll = lane & 15;
  const int n0 = blockIdx.x * 64;

  #pragma unroll
  for (int it = 0; it < 7; ++it) {
    int ch = tid + it * 512;
    int rr = ch / 56;
    int cc = (ch - rr * 56) * 8;
    s8v vals = {0, 0, 0, 0, 0, 0, 0, 0};
    int node = n0 + rr;
    if (node < NN) {
      if (cc < 256) {
        vals = *(const s8v*)(xbf + (size_t)node * ND + cc);
      } else if (cc < 384) {
        vals = *(const s8v*)(aggbf + (size_t)node * ED + (cc - 256));
      } else {
        const float* up = u + (size_t)batch[node] * GD + (cc - 384);
        const float4 v0 = *(const float4*)(up);
        const float4 v1 = *(const float4*)(up + 4);
        vals[0] = f2bf(v0.x); vals[1] = f2bf(v0.y); vals[2] = f2bf(v0.z); vals[3] = f2bf(v0.w);
        vals[4] = f2bf(v1.x); vals[5] = f2bf(v1.y); vals[6] = f2bf(v1.z); vals[7] = f2bf(v1.w);
      }
    }
    int byte = (rr * 896 + cc * 2) ^ ((rr & 7) << 4);
    *(s8v*)((char*)smem + byte) = vals;
  }
  __syncthreads();

  f4v acc3[8][4];
  #pragma unroll
  for (int n = 0; n < 8; ++n)
    #pragma unroll
    for (int m = 0; m < 4; ++m)
      acc3[n][m] = (f4v){0.f, 0.f, 0.f, 0.f};

  for (int ks = 0; ks < 14; ++ks) {
    s8v af[4];
    #pragma unroll
    for (int m = 0; m < 4; ++m) {
      int row = 16 * m + ll;
      int byte = (row * 896 + ks * 64 + lh * 16) ^ ((row & 7) << 4);
      af[m] = *(const s8v*)((const char*)smem + byte);
    }
    #pragma unroll
    for (int n = 0; n < 8; ++n) {
      s8v wf = *(const s8v*)(w3p + (((ks * 1024 + w * 128 + 16 * n + ll) * 4 + lh) << 3));
      #pragma unroll
      for (int m = 0; m < 4; ++m)
        acc3[n][m] = __builtin_amdgcn_mfma_f32_16x16x32_bf16(wf, af[m], acc3[n][m], 0, 0, 0);
    }
  }
  __syncthreads();

  #pragma unroll
  for (int n = 0; n < 8; ++n) {
    int cb = w * 128 + 16 * n + 4 * lh;
    const float4 bv = *(const float4*)(b3 + cb);
    #pragma unroll
    for (int m = 0; m < 4; ++m) {
      int row = 16 * m + ll;
      s4v o;
      float v0 = acc3[n][m][0] + bv.x; o[0] = f2bf(v0 > 0.f ? v0 : 0.f);
      float v1 = acc3[n][m][1] + bv.y; o[1] = f2bf(v1 > 0.f ? v1 : 0.f);
      float v2 = acc3[n][m][2] + bv.z; o[2] = f2bf(v2 > 0.f ? v2 : 0.f);
      float v3 = acc3[n][m][3] + bv.w; o[3] = f2bf(v3 > 0.f ? v3 : 0.f);
      int byte = (row * 2048 + cb * 2) ^ ((row & 7) << 4);
      *(s4v*)((char*)smem + byte) = o;
    }
  }
  __syncthreads();

  f4v acc4[2][4];
  #pragma unroll
  for (int n = 0; n < 2; ++n)
    #pragma unroll
    for (int m = 0; m < 4; ++m)
      acc4[n][m] = (f4v){0.f, 0.f, 0.f, 0.f};

  for (int ks = 0; ks < 32; ++ks) {
    s8v hf[4];
    #pragma unroll
    for (int m = 0; m < 4; ++m) {
      int row = 16 * m + ll;
      int byte = (row * 2048 + ks * 64 + lh * 16) ^ ((row & 7) << 4);
      hf[m] = *(const s8v*)((const char*)smem + byte);
    }
    #pragma unroll
    for (int n = 0; n < 2; ++n) {
      s8v wf = *(const s8v*)(w4p + (((ks * 256 + w * 32 + 16 * n + ll) * 4 + lh) << 3));
      #pragma unroll
      for (int m = 0; m < 4; ++m)
        acc4[n][m] = __builtin_amdgcn_mfma_f32_16x16x32_bf16(wf, hf[m], acc4[n][m], 0, 0, 0);
    }
  }
  __syncthreads();

  float* yb = (float*)smem;
  #pragma unroll
  for (int n = 0; n < 2; ++n) {
    int cb = w * 32 + 16 * n + 4 * lh;
    const float4 bv = *(const float4*)(b4 + cb);
    #pragma unroll
    for (int m = 0; m < 4; ++m) {
      int row = 16 * m + ll;
      int node = n0 + row;
      float4 xv = {0.f, 0.f, 0.f, 0.f};
      if (node < NN) xv = *(const float4*)(x + (size_t)node * ND + cb);
      f4v o;
      o[0] = acc4[n][m][0] + bv.x + xv.x;
      o[1] = acc4[n][m][1] + bv.y + xv.y;
      o[2] = acc4[n][m][2] + bv.z + xv.z;
      o[3] = acc4[n][m][3] + bv.w + xv.w;
      *(f4v*)(yb + row * 260 + cb) = o;
    }
  }
  __syncthreads();

  {
    int row = tid >> 3, sub = tid & 7;
    int node = n0 + row;
    float v[32];
    float sum = 0.f, ssq = 0.f;
    #pragma unroll
    for (int i = 0; i < 8; ++i) {
      const float4 t = *(const float4*)(yb + row * 260 + (i * 8 + sub) * 4);
      v[i * 4 + 0] = t.x; v[i * 4 + 1] = t.y; v[i * 4 + 2] = t.z; v[i * 4 + 3] = t.w;
      sum += t.x + t.y + t.z + t.w;
      ssq += t.x * t.x + t.y * t.y + t.z * t.z + t.w * t.w;
    }
    #pragma unroll
    for (int d = 1; d < 8; d <<= 1) {
      sum += __shfl_xor(sum, d);
      ssq += __shfl_xor(ssq, d);
    }
    float mu = sum * (1.f / 256.f);
    float var = ssq * (1.f / 256.f) - mu * mu;
    float rstd = rsqrtf(var + 1e-5f);
    if (node < NN) {
      #pragma unroll
      for (int i = 0; i < 8; ++i) {
        int c = (i * 8 + sub) * 4;
        const float4 g = *(const float4*)(gamma + c);
        const float4 be = *(const float4*)(beta + c);
        float4 o;
        o.x = (v[i * 4 + 0] - mu) * rstd * g.x + be.x;
        o.y = (v[i * 4 + 1] - mu) * rstd * g.y + be.y;
        o.z = (v[i * 4 + 2] - mu) * rstd * g.z + be.z;
        o.w = (v[i * 4 + 3] - mu) * rstd * g.w + be.w;
        *(float4*)(out + (size_t)node * ND + c) = o;
      }
    }
  }
}

extern "C" void kernel_launch(void* const* d_in, const int* in_sizes, int n_in,
                              void* d_out, int out_size, void* d_ws, size_t ws_size,
                              hipStream_t stream) {
  const float* x    = (const float*)d_in[0];
  const float* ea   = (const float*)d_in[1];
  const float* u    = (const float*)d_in[2];
  const float* W1   = (const float*)d_in[3];
  const float* b1   = (const float*)d_in[4];
  const float* W2   = (const float*)d_in[5];
  const float* b2   = (const float*)d_in[6];
  const float* W3   = (const float*)d_in[7];
  const float* b3   = (const float*)d_in[8];
  const float* W4   = (const float*)d_in[9];
  const float* b4   = (const float*)d_in[10];
  const float* gamma = (const float*)d_in[11];
  const float* beta  = (const float*)d_in[12];
  const int* eidx   = (const int*)d_in[13];
  const int* batch  = (const int*)d_in[14];
  float* out = (float*)d_out;

  char* p = (char*)d_ws;
  size_t off = 0;
  auto take = [&](size_t n) { char* r = p + off; off = (off + n + 255) & ~(size_t)255; return r; };
  short* xbf = (short*)take((size_t)NN * ND * 2);
  short* w1p = (short*)take((size_t)384 * 512 * 2);
  short* w2p = (short*)take((size_t)512 * 128 * 2);
  short* w3p = (short*)take((size_t)448 * 1024 * 2);
  short* w4p = (short*)take((size_t)1024 * 256 * 2);
  unsigned int* cnt = (unsigned int*)take((size_t)NN * 4);
  int* elist = (int*)take((size_t)NN * MAXDEG * 4);
  unsigned short* aggbf = (unsigned short*)take((size_t)NN * ED * 2);
  unsigned short* ebuf = (unsigned short*)take((size_t)NE * ED * 2);

  const int* erow = eidx;
  const int* ecol = eidx + NE;

  cvt_bf16_kernel<<<(NN * ND / 4 + 255) / 256, 256, 0, stream>>>(x, xbf, NN * ND);
  pack_w_kernel<<<(384 * 512 + 255) / 256, 256, 0, stream>>>(W1, w1p, 384, 512);
  pack_w_kernel<<<(512 * 128 + 255) / 256, 256, 0, stream>>>(W2, w2p, 512, 128);
  pack_w_kernel<<<(448 * 1024 + 255) / 256, 256, 0, stream>>>(W3, w3p, 448, 1024);
  pack_w_kernel<<<(1024 * 256 + 255) / 256, 256, 0, stream>>>(W4, w4p, 1024, 256);
  hipMemsetAsync(cnt, 0, (size_t)NN * 4, stream);
  build_kernel<<<(NE + 255) / 256, 256, 0, stream>>>(ecol, cnt, elist);

  edge_kernel<<<(NE + 127) / 128, 1024, 0, stream>>>(xbf, ea, w1p, b1, w2p, b2, erow, ebuf);
  agg_kernel<<<(NN + 3) / 4, 256, 0, stream>>>(ebuf, elist, cnt, aggbf);
  node_kernel<<<(NN + 63) / 64, 512, 0, stream>>>(x, xbf, u, w3p, b3, w4p, b4,
                                                  gamma, beta, batch, aggbf, out);
}